// Round 3
// baseline (132.866 us; speedup 1.0000x reference)
//
#include <hip/hip_runtime.h>

#define SEQ   1024
#define BATCH 32
#define DIM   256   // 64 float4 per row

typedef float vfloat4 __attribute__((ext_vector_type(4)));

// ---------------------------------------------------------------------------
// Kernel 1: per-batch inclusive scan of durations (1024 tokens, 1024 threads,
// 1 token each, LDS Hillis-Steele), then scatter within-token position as a
// BYTE into batch-major pos8[b*T + f] -- each block writes one contiguous
// byte range (durations < 8, so position fits uint8). Also writes totals[b].
// pos8 needs NO init: rows f >= totals[b] are never read by the gather.
// ---------------------------------------------------------------------------
__global__ __launch_bounds__(1024) void pe_scan_scatter(const int* __restrict__ dur,
                                                        unsigned char* __restrict__ pos8,
                                                        int* __restrict__ totals,
                                                        int T) {
    const int b = blockIdx.x;    // batch element, 0..31
    const int t = threadIdx.x;   // token index, 0..1023
    __shared__ int ssum[SEQ];

    const int d = dur[t * BATCH + b];
    ssum[t] = d;
    __syncthreads();

    // Hillis-Steele inclusive scan over 1024 elements (10 rounds)
    for (int off = 1; off < SEQ; off <<= 1) {
        int v = (t >= off) ? ssum[t - off] : 0;
        __syncthreads();
        ssum[t] += v;
        __syncthreads();
    }

    if (t == SEQ - 1) totals[b] = ssum[t];

    int start = ssum[t] - d;                 // exclusive prefix
    unsigned char* dst = pos8 + (size_t)b * T;
    for (int k = 0; k < d; ++k) {            // d in [0, 8)
        int f = start + k;
        if (f < T) dst[f] = (unsigned char)k;
    }
}

// ---------------------------------------------------------------------------
// Kernel 2: gather. One float4 (16B) per thread, fully coalesced nontemporal
// stores (output is write-once, never re-read). Each 64-lane wave covers
// exactly one (frame, batch) row -> pos8/totals loads are wave-uniform
// broadcasts. Only encoding rows 0..7 are touched -> L1-resident.
// ---------------------------------------------------------------------------
__global__ __launch_bounds__(256) void pe_gather(const unsigned char* __restrict__ pos8,
                                                 const int* __restrict__ totals,
                                                 const vfloat4* __restrict__ enc,
                                                 vfloat4* __restrict__ out,
                                                 int n4, int T) {
    int idx = blockIdx.x * blockDim.x + threadIdx.x;
    if (idx >= n4) return;
    int row = idx >> 6;          // (frame, batch) row
    int f   = row >> 5;          // frame index  (BATCH == 32)
    int b   = row & 31;          // batch index
    vfloat4 v = {0.f, 0.f, 0.f, 0.f};
    if (f < totals[b]) {
        int p = pos8[(size_t)b * T + f];     // within-token position, 0..7
        v = enc[p * (DIM / 4) + (idx & 63)];
    }
    __builtin_nontemporal_store(v, &out[idx]);
}

extern "C" void kernel_launch(void* const* d_in, const int* in_sizes, int n_in,
                              void* d_out, int out_size, void* d_ws, size_t ws_size,
                              hipStream_t stream) {
    const int*   dur = (const int*)d_in[0];     // (SEQ, BATCH) int32
    const float* enc = (const float*)d_in[1];   // (1000, DIM) float32

    const int T = out_size / (BATCH * DIM);

    int*           totals = (int*)d_ws;                   // 32 ints
    unsigned char* pos8   = (unsigned char*)d_ws + 128;   // BATCH*T bytes

    pe_scan_scatter<<<BATCH, 1024, 0, stream>>>(dur, pos8, totals, T);

    const int n4 = T * BATCH * (DIM / 4);
    pe_gather<<<(n4 + 255) / 256, 256, 0, stream>>>(
        pos8, totals, (const vfloat4*)enc, (vfloat4*)d_out, n4, T);
}